// Round 1
// baseline (143.963 us; speedup 1.0000x reference)
//
#include <hip/hip_runtime.h>

// KPConv as bf16 MFMA GEMM: OUT[p,o] = sum_j C[p,j] * W2[j,o]
//   j = k*3+i (48, padded to 64), C[p,j] = g[p,k]*x[p,i], W2 = weights flat [48][64].
// Block = 256 threads = 256 points. Phase A: per-thread C-row -> LDS in MFMA
// A-fragment layout. Phase B: 4 waves x 4 tiles x (2 MFMA x 4 o-tiles).

typedef __bf16  bf16x8 __attribute__((ext_vector_type(8)));
typedef float   f32x4  __attribute__((ext_vector_type(4)));
typedef unsigned int   u32x4  __attribute__((ext_vector_type(4)));

union OctU {
    unsigned short s[8];
    u32x4          u4;
    bf16x8         v;
};

__device__ __forceinline__ unsigned short f2bf(float f) {
    unsigned u = __builtin_bit_cast(unsigned, f);
    u += 0x7FFFu + ((u >> 16) & 1u);   // round-to-nearest-even
    return (unsigned short)(u >> 16);
}

__global__ __launch_bounds__(256) void kpconv_mfma(
    const float* __restrict__ x,       // [P][3]
    const float* __restrict__ kp,      // [16][3]
    const float* __restrict__ w,       // [48][64] (= [16][3][64])
    const float* __restrict__ sigma,   // [1]
    float* __restrict__ out)           // [P][64]
{
    // 2048 chunks of 16B (16 tiles * 2 khalf * 4 quad * 16 m) + pad every 8
    __shared__ u32x4 ldsA[2304];

    const int tid  = threadIdx.x;
    const int lane = tid & 63;
    const int wv   = tid >> 6;
    const int q    = lane >> 4;   // quad within wave
    const int n16  = lane & 15;
    const long long base = (long long)blockIdx.x * 256;

    // ---- B fragments (weights), resident in VGPRs for the whole block ----
    // B[k = h*32 + q*8 + j][n = ot*16 + n16], zero-padded for k >= 48.
    bf16x8 bfrag[2][4];
#pragma unroll
    for (int h = 0; h < 2; ++h) {
#pragma unroll
        for (int ot = 0; ot < 4; ++ot) {
            OctU o;
#pragma unroll
            for (int j = 0; j < 8; ++j) {
                int kk = h * 32 + q * 8 + j;
                float v = (kk < 48) ? w[kk * 64 + ot * 16 + n16] : 0.0f;
                o.s[j] = f2bf(v);
            }
            bfrag[h][ot] = o.v;
        }
    }

    // ---- Phase A: this thread's point -> bf16 C-row in LDS ----
    {
        const float sg = sigma[0];
        // exp(-0.5*d2/s^2) = exp2(d2 * (-0.5*log2e)/s^2)
        const float scale = -0.72134752f / (sg * sg);
        const long long p = base + tid;
        float xv[3];
        xv[0] = x[p * 3 + 0];
        xv[1] = x[p * 3 + 1];
        xv[2] = x[p * 3 + 2];
        float g[16];
#pragma unroll
        for (int k = 0; k < 16; ++k) {
            float dx = xv[0] - kp[k * 3 + 0];
            float dy = xv[1] - kp[k * 3 + 1];
            float dz = xv[2] - kp[k * 3 + 2];
            float d2 = dx * dx + dy * dy + dz * dz;
            g[k] = exp2f(d2 * scale);
        }
        const int tile = tid >> 4;
        const int m    = tid & 15;
#pragma unroll
        for (int o = 0; o < 8; ++o) {      // octet o covers j = 8o..8o+7
            OctU ou;
#pragma unroll
            for (int j8 = 0; j8 < 8; ++j8) {
                int j = o * 8 + j8;
                ou.s[j8] = (j < 48) ? f2bf(g[j / 3] * xv[j % 3])
                                    : (unsigned short)0;  // zero K-pad (LDS is poison!)
            }
            int chunk = tile * 128 + (o >> 2) * 64 + (o & 3) * 16 + m;
            ldsA[chunk + (chunk >> 3)] = ou.u4;
        }
    }
    __syncthreads();

    // ---- Phase B: wave wv handles 16-point tiles wv*4 .. wv*4+3 ----
#pragma unroll
    for (int t4 = 0; t4 < 4; ++t4) {
        const int t  = wv * 4 + t4;
        const int c0 = t * 128 + q * 16 + n16;  // khalf 0
        const int c1 = c0 + 64;                 // khalf 1
        OctU a0u, a1u;
        a0u.u4 = ldsA[c0 + (c0 >> 3)];
        a1u.u4 = ldsA[c1 + (c1 >> 3)];
        f32x4 acc[4];
#pragma unroll
        for (int ot = 0; ot < 4; ++ot) {
            acc[ot] = (f32x4){0.f, 0.f, 0.f, 0.f};
            acc[ot] = __builtin_amdgcn_mfma_f32_16x16x32_bf16(a0u.v, bfrag[0][ot], acc[ot], 0, 0, 0);
            acc[ot] = __builtin_amdgcn_mfma_f32_16x16x32_bf16(a1u.v, bfrag[1][ot], acc[ot], 0, 0, 0);
        }
        // D: lane holds OUT[row = q*4 + r][col = ot*16 + n16] of this tile
        const long long prow = base + t * 16 + q * 4;
#pragma unroll
        for (int ot = 0; ot < 4; ++ot) {
#pragma unroll
            for (int r = 0; r < 4; ++r) {
                out[(prow + r) * 64 + ot * 16 + n16] = acc[ot][r];
            }
        }
    }
}

extern "C" void kernel_launch(void* const* d_in, const int* in_sizes, int n_in,
                              void* d_out, int out_size, void* d_ws, size_t ws_size,
                              hipStream_t stream) {
    const float* x     = (const float*)d_in[0];
    const float* kp    = (const float*)d_in[1];
    const float* w     = (const float*)d_in[2];
    const float* sigma = (const float*)d_in[3];
    float* out = (float*)d_out;

    const int npoints = in_sizes[0] / 3;      // B*N = 524288
    const int blocks  = npoints / 256;        // 2048, exact
    kpconv_mfma<<<blocks, 256, 0, stream>>>(x, kp, w, sigma, out);
}